// Round 5
// baseline (184.648 us; speedup 1.0000x reference)
//
#include <hip/hip_runtime.h>
#include <math.h>

#define NEG_SLOPE 0.1f

typedef __attribute__((ext_vector_type(8))) short short8;
typedef __attribute__((ext_vector_type(4))) short short4v;
typedef __attribute__((ext_vector_type(4))) float floatx4;

__device__ __forceinline__ float lrelu(float x) { return x >= 0.0f ? x : NEG_SLOPE * x; }

// fp32 -> bf16 round-to-nearest-even
__device__ __forceinline__ unsigned short f2bf(float x) {
  unsigned u = __float_as_uint(x);
  return (unsigned short)((u + 0x7fffu + ((u >> 16) & 1u)) >> 16);
}

__device__ __forceinline__ float wave_sum64(float v) {
  #pragma unroll
  for (int s = 32; s > 0; s >>= 1) v += __shfl_xor(v, s, 64);
  return v;
}

// ---------------------------------------------------------------------------
// prep: entire per-batch vector chain in ONE kernel. Grid 16 x 256 thr.
// ---------------------------------------------------------------------------
__global__ __launch_bounds__(256) void prep_kernel(
    const float* __restrict__ deg, const float* __restrict__ W_size,
    const float* __restrict__ W_k1, const float* __restrict__ W_k2,
    const float* __restrict__ W_ac, const float* __restrict__ W_du1,
    const float* __restrict__ W_du2, float* __restrict__ kern_ws,
    float* __restrict__ att_ws) {
  const int b = blockIdx.x;
  const int t = threadIdx.x;
  __shared__ float dvec[512];
  __shared__ float fbuf[64], fabuf[64];
  __shared__ float t1s[8], t2s[8];

  // ---- A: dvec (2 threads/row, 8 indep float4 each, 4 rows/thread) ----
  const float* degb = deg + (size_t)b * 32768;
  const int half = t & 1, row0 = t >> 1;
  #pragma unroll
  for (int u = 0; u < 4; ++u) {
    const int d = row0 + u * 128;
    const float* p = degb + (size_t)d * 64 + half * 32;
    float4 x0 = *(const float4*)(p);
    float4 x1 = *(const float4*)(p + 4);
    float4 x2 = *(const float4*)(p + 8);
    float4 x3 = *(const float4*)(p + 12);
    float4 x4 = *(const float4*)(p + 16);
    float4 x5 = *(const float4*)(p + 20);
    float4 x6 = *(const float4*)(p + 24);
    float4 x7 = *(const float4*)(p + 28);
    float s = (x0.x + x0.y + x0.z + x0.w) + (x1.x + x1.y + x1.z + x1.w) +
              (x2.x + x2.y + x2.z + x2.w) + (x3.x + x3.y + x3.z + x3.w) +
              (x4.x + x4.y + x4.z + x4.w) + (x5.x + x5.y + x5.z + x5.w) +
              (x6.x + x6.y + x6.z + x6.w) + (x7.x + x7.y + x7.z + x7.w);
    s += __shfl_xor(s, 1, 64);
    if (half == 0) dvec[d] = s * (1.0f / 64.0f);
  }
  __syncthreads();

  // ---- B: f / fa (4 threads per channel, float4, 32 iters) ----
  {
    const int c = t >> 2, q = t & 3;
    const float* w1 = W_size + (size_t)c * 512;
    const float* w2 = W_ac + (size_t)c * 512;
    float p1 = 0.0f, p2 = 0.0f;
    #pragma unroll 4
    for (int kk = 0; kk < 32; ++kk) {
      const int e = kk * 16 + q * 4;
      float4 d4 = *(const float4*)&dvec[e];
      float4 a4 = *(const float4*)(w1 + e);
      float4 b4 = *(const float4*)(w2 + e);
      p1 += d4.x * a4.x + d4.y * a4.y + d4.z * a4.z + d4.w * a4.w;
      p2 += d4.x * b4.x + d4.y * b4.y + d4.z * b4.z + d4.w * b4.w;
    }
    p1 += __shfl_xor(p1, 1, 64); p1 += __shfl_xor(p1, 2, 64);
    p2 += __shfl_xor(p2, 1, 64); p2 += __shfl_xor(p2, 2, 64);
    if (q == 0) { fbuf[c] = p1; fabuf[c] = p2; }
  }
  __syncthreads();

  // ---- C: t1/t2 (wave 0 / wave 1) ----
  const int wave = t >> 6, lane = t & 63;
  if (wave == 0) {
    float v = fbuf[lane];
    #pragma unroll
    for (int rr = 0; rr < 8; ++rr) {
      float p = wave_sum64(v * W_k1[rr * 64 + lane]);
      if (lane == 0) t1s[rr] = lrelu(p);
    }
  } else if (wave == 1) {
    float v = fabuf[lane];
    #pragma unroll
    for (int rr = 0; rr < 8; ++rr) {
      float p = wave_sum64(v * W_du1[rr * 64 + lane]);
      if (lane == 0) t2s[rr] = lrelu(p);
    }
  }
  __syncthreads();

  // ---- D: kern [576], att [64] ----
  for (int i = t; i < 576; i += 256) {
    float4 wa0 = *(const float4*)&W_k2[i * 8];
    float4 wa1 = *(const float4*)&W_k2[i * 8 + 4];
    kern_ws[b * 576 + i] =
        t1s[0] * wa0.x + t1s[1] * wa0.y + t1s[2] * wa0.z + t1s[3] * wa0.w +
        t1s[4] * wa1.x + t1s[5] * wa1.y + t1s[6] * wa1.z + t1s[7] * wa1.w;
  }
  if (t < 64) {
    float4 wa0 = *(const float4*)&W_du2[t * 8];
    float4 wa1 = *(const float4*)&W_du2[t * 8 + 4];
    float s = t2s[0] * wa0.x + t2s[1] * wa0.y + t2s[2] * wa0.z + t2s[3] * wa0.w +
              t2s[4] * wa1.x + t2s[5] * wa1.y + t2s[6] * wa1.z + t2s[7] * wa1.w;
    att_ws[b * 64 + t] = 1.0f / (1.0f + expf(-s));
  }
}

// ---------------------------------------------------------------------------
// fused: dw3x3+lrelu (fp32) + 1x1 conv (bf16 MFMA, A=z) + epilogue.
// Grid 2048 x 256 thr; ONE (b,h) row per block; b = bid>>7, h = bid&127.
// R5: (1) all 24 phase-1 float4 loads hoisted before compute (MLP),
//     (2) epilogue feat loads hoisted to phase-2 start (L2-hot re-read,
//         latency hidden under ds_read+MFMA).
// __launch_bounds__(256,4): 128-VGPR cap, 4 blocks/CU.
// ---------------------------------------------------------------------------
__global__ __launch_bounds__(256, 4) void fused_kernel(
    const float* __restrict__ feat, const float* __restrict__ W_conv,
    const float* __restrict__ b_conv, const float* __restrict__ kern_ws,
    const float* __restrict__ att_ws, float* __restrict__ out) {
  const int bid = blockIdx.x;
  const int b = bid >> 7;
  const int h = bid & 127;

  const int t = threadIdx.x;

  __shared__ __align__(16) unsigned short zT[128 * 72];
  __shared__ __align__(16) unsigned short wt[64 * 72];
  __shared__ float ks[576];
  __shared__ float atts[64];
  __shared__ float bcs[64];

  // ---- stage wt (bf16, swizzled), ks, atts, bcs ----
  {
    const int o = t >> 2;
    const int c0 = (t & 3) * 16;
    const float* wp = W_conv + o * 64 + c0;
    float4 a0 = *(const float4*)(wp);
    float4 a1 = *(const float4*)(wp + 4);
    float4 a2 = *(const float4*)(wp + 8);
    float4 a3 = *(const float4*)(wp + 12);
    const int sw = ((o >> 2) ^ (o >> 5)) & 7;
    short8 p0, p1;
    p0[0] = f2bf(a0.x); p0[1] = f2bf(a0.y); p0[2] = f2bf(a0.z); p0[3] = f2bf(a0.w);
    p0[4] = f2bf(a1.x); p0[5] = f2bf(a1.y); p0[6] = f2bf(a1.z); p0[7] = f2bf(a1.w);
    p1[0] = f2bf(a2.x); p1[1] = f2bf(a2.y); p1[2] = f2bf(a2.z); p1[3] = f2bf(a2.w);
    p1[4] = f2bf(a3.x); p1[5] = f2bf(a3.y); p1[6] = f2bf(a3.z); p1[7] = f2bf(a3.w);
    const int kc0 = ((c0 >> 3) + 0) ^ sw;
    const int kc1 = ((c0 >> 3) + 1) ^ sw;
    *(short8*)&wt[o * 72 + kc0 * 8] = p0;
    *(short8*)&wt[o * 72 + kc1 * 8] = p1;
  }
  for (int i = t; i < 576; i += 256) ks[i] = kern_ws[b * 576 + i];
  if (t < 64) { atts[t] = att_ws[b * 64 + t]; bcs[t] = b_conv[t]; }

  const size_t base_b = (size_t)b * 64 * 128 * 128;
  const int lane = t & 63, wave = t >> 6;
  const int cq = t >> 5;        // 0..7: channel quad group
  const int gg = t & 31;        // w-group, w0 = gg*4
  const int w0 = gg * 4;
  const int swz = (gg ^ (gg >> 3)) & 7;
  const float4 zf4 = {0.f, 0.f, 0.f, 0.f};

  const bool hgt0 = (h > 0), hlt = (h < 127);
  const float* fbase = feat + base_b + (size_t)h * 128 + w0;

  // ---- Phase 1 loads: ALL 24 float4 issued before any compute (MLP) ----
  float4 top[2][4], mid[2][4], bot[2][4];
  #pragma unroll
  for (int it = 0; it < 2; ++it) {
    const int c0 = cq * 4 + it * 32;
    #pragma unroll
    for (int j = 0; j < 4; ++j) {
      const float* p = fbase + (size_t)(c0 + j) * 16384;
      mid[it][j] = *(const float4*)p;
      top[it][j] = hgt0 ? *(const float4*)(p - 128) : zf4;
      bot[it][j] = hlt  ? *(const float4*)(p + 128) : zf4;
    }
  }
  __syncthreads();  // covers wt/ks/atts staging

  // ---- Phase 1 compute: dw3x3 + lrelu -> zT (bf16, b64 writes) ----
  #pragma unroll
  for (int it = 0; it < 2; ++it) {
    const int c0 = cq * 4 + it * 32;
    unsigned short sres[4][4];
    #pragma unroll
    for (int j = 0; j < 4; ++j) {
      const float* kv = &ks[(c0 + j) * 9];
      const float k0 = kv[0], k1 = kv[1], k2 = kv[2];
      const float k3 = kv[3], k4 = kv[4], k5 = kv[5];
      const float k6 = kv[6], k7 = kv[7], k8 = kv[8];
      float a0 = 0.f, a1 = 0.f, a2 = 0.f, a3 = 0.f;
      {
        float4 m = top[it][j];
        float lf = __shfl(m.w, lane - 1, 64); if (gg == 0)  lf = 0.f;
        float rt = __shfl(m.x, lane + 1, 64); if (gg == 31) rt = 0.f;
        a0 += k0 * lf  + k1 * m.x + k2 * m.y;
        a1 += k0 * m.x + k1 * m.y + k2 * m.z;
        a2 += k0 * m.y + k1 * m.z + k2 * m.w;
        a3 += k0 * m.z + k1 * m.w + k2 * rt;
      }
      {
        float4 m = mid[it][j];
        float lf = __shfl(m.w, lane - 1, 64); if (gg == 0)  lf = 0.f;
        float rt = __shfl(m.x, lane + 1, 64); if (gg == 31) rt = 0.f;
        a0 += k3 * lf  + k4 * m.x + k5 * m.y;
        a1 += k3 * m.x + k4 * m.y + k5 * m.z;
        a2 += k3 * m.y + k4 * m.z + k5 * m.w;
        a3 += k3 * m.z + k4 * m.w + k5 * rt;
      }
      {
        float4 m = bot[it][j];
        float lf = __shfl(m.w, lane - 1, 64); if (gg == 0)  lf = 0.f;
        float rt = __shfl(m.x, lane + 1, 64); if (gg == 31) rt = 0.f;
        a0 += k6 * lf  + k7 * m.x + k8 * m.y;
        a1 += k6 * m.x + k7 * m.y + k8 * m.z;
        a2 += k6 * m.y + k7 * m.z + k8 * m.w;
        a3 += k6 * m.z + k7 * m.w + k8 * rt;
      }
      sres[j][0] = f2bf(lrelu(a0));
      sres[j][1] = f2bf(lrelu(a1));
      sres[j][2] = f2bf(lrelu(a2));
      sres[j][3] = f2bf(lrelu(a3));
    }
    const int chunk = (cq >> 1) + it * 4;
    const int kcs = ((chunk ^ swz) * 8) + (cq & 1) * 4;
    #pragma unroll
    for (int i = 0; i < 4; ++i) {
      short4v sv;
      sv[0] = (short)sres[0][i]; sv[1] = (short)sres[1][i];
      sv[2] = (short)sres[2][i]; sv[3] = (short)sres[3][i];
      *(short4v*)&zT[(w0 + i) * 72 + kcs] = sv;
    }
  }
  __syncthreads();

  // ---- Phase 2: 1x1 conv via MFMA (A=z -> D rows are w) + epilogue ----
  {
    const int r = lane & 15, q = lane >> 4;

    // Hoisted epilogue feat loads: lines are L2-hot from phase 1, latency
    // hidden under the ds_reads + MFMAs below.
    float4 fv[2][4];
    #pragma unroll
    for (int wm2 = 0; wm2 < 2; ++wm2) {
      const int wb = (wave * 2 + wm2) * 16 + q * 4;
      #pragma unroll
      for (int nt = 0; nt < 4; ++nt) {
        const int o = nt * 16 + r;
        fv[wm2][nt] = *(const float4*)(feat + base_b + (size_t)o * 16384 +
                                       (size_t)h * 128 + wb);
      }
    }

    short8 az[2][2];
    #pragma unroll
    for (int wm2 = 0; wm2 < 2; ++wm2) {
      const int w = (wave * 2 + wm2) * 16 + r;
      const int sz = ((w >> 2) ^ (w >> 5)) & 7;
      #pragma unroll
      for (int ksp = 0; ksp < 2; ++ksp) {
        const int kc = (ksp * 4 + q) ^ sz;
        az[wm2][ksp] = *(const short8*)&zT[w * 72 + kc * 8];
      }
    }

    floatx4 acc[2][4];
    #pragma unroll
    for (int wm2 = 0; wm2 < 2; ++wm2)
      #pragma unroll
      for (int nt = 0; nt < 4; ++nt) acc[wm2][nt] = (floatx4){0.f, 0.f, 0.f, 0.f};

    #pragma unroll
    for (int nt = 0; nt < 4; ++nt) {
      const int o = nt * 16 + r;
      const int so = ((o >> 2) ^ (o >> 5)) & 7;
      #pragma unroll
      for (int ksp = 0; ksp < 2; ++ksp) {
        const int kc = (ksp * 4 + q) ^ so;
        short8 bw = *(const short8*)&wt[o * 72 + kc * 8];
        #pragma unroll
        for (int wm2 = 0; wm2 < 2; ++wm2)
          acc[wm2][nt] = __builtin_amdgcn_mfma_f32_16x16x32_bf16(
              az[wm2][ksp], bw, acc[wm2][nt], 0, 0, 0);
      }
    }

    #pragma unroll
    for (int wm2 = 0; wm2 < 2; ++wm2) {
      const int wb = (wave * 2 + wm2) * 16 + q * 4;
      #pragma unroll
      for (int nt = 0; nt < 4; ++nt) {
        const int o = nt * 16 + r;
        const size_t off = base_b + (size_t)o * 16384 + (size_t)h * 128 + wb;
        const float at = atts[o], bo = bcs[o];
        floatx4 a = acc[wm2][nt];
        float4 fvv = fv[wm2][nt];
        float4 ov;
        ov.x = a[0] + bo + at * fvv.x;
        ov.y = a[1] + bo + at * fvv.y;
        ov.z = a[2] + bo + at * fvv.z;
        ov.w = a[3] + bo + at * fvv.w;
        *(float4*)(out + off) = ov;
      }
    }
  }
}

extern "C" void kernel_launch(void* const* d_in, const int* in_sizes, int n_in,
                              void* d_out, int out_size, void* d_ws, size_t ws_size,
                              hipStream_t stream) {
  const float* feat   = (const float*)d_in[0];
  const float* deg    = (const float*)d_in[1];
  const float* W_size = (const float*)d_in[2];
  const float* W_k1   = (const float*)d_in[3];
  const float* W_k2   = (const float*)d_in[4];
  const float* W_conv = (const float*)d_in[5];
  const float* b_conv = (const float*)d_in[6];
  const float* W_ac   = (const float*)d_in[7];
  const float* W_du1  = (const float*)d_in[8];
  const float* W_du2  = (const float*)d_in[9];
  float* out = (float*)d_out;

  float* kern_ws = (float*)d_ws;            // 16*576
  float* att_ws  = kern_ws + 16 * 576;      // 16*64

  prep_kernel<<<16, 256, 0, stream>>>(deg, W_size, W_k1, W_k2, W_ac, W_du1,
                                      W_du2, kern_ws, att_ws);
  fused_kernel<<<2048, 256, 0, stream>>>(feat, W_conv, b_conv, kern_ws, att_ws,
                                         out);
}